// Round 8
// baseline (207.800 us; speedup 1.0000x reference)
//
#include <hip/hip_runtime.h>
#include <math.h>

#define B_ 16
#define C_ 64
#define H_ 256
#define W_ 256
#define HW_ 65536

typedef __attribute__((ext_vector_type(4))) float f4v;
typedef __attribute__((ext_vector_type(2))) float f2v;
typedef __attribute__((ext_vector_type(2))) unsigned int u2v;

__device__ __forceinline__ float waveSum(float v) {
#pragma unroll
    for (int o = 32; o > 0; o >>= 1) v += __shfl_down(v, o, 64);
    return v;
}
__device__ __forceinline__ float waveMax(float v) {
#pragma unroll
    for (int o = 32; o > 0; o >>= 1) v = fmaxf(v, __shfl_down(v, o, 64));
    return v;
}

// K1: half-plane partial sum & max of weight; transcode -> fp8 e4m3 copy.
// grid=2048 (2 blocks per (b,c) plane), 512 thr.
__global__ __launch_bounds__(512) void reduce_weight_q(const float* __restrict__ w,
                              u2v* __restrict__ wq,
                              float* __restrict__ wsum2, float* __restrict__ wmax2) {
    int blk = blockIdx.x;
    int bc = blk >> 1, half = blk & 1;
    const f4v* p = (const f4v*)(w + (size_t)bc * HW_ + half * (HW_ / 2));
    u2v* q = wq + (size_t)bc * (HW_ / 8) + half * (HW_ / 16);
    float s = 0.f, m = -INFINITY;
#pragma unroll 4
    for (int i = threadIdx.x; i < HW_ / 16; i += 512) {
        f4v a = __builtin_nontemporal_load(p + 2 * i);
        f4v c = __builtin_nontemporal_load(p + 2 * i + 1);
        s += (a.x + a.y) + (a.z + a.w) + (c.x + c.y) + (c.z + c.w);
        m = fmaxf(m, fmaxf(fmaxf(a.x, a.y), fmaxf(a.z, a.w)));
        m = fmaxf(m, fmaxf(fmaxf(c.x, c.y), fmaxf(c.z, c.w)));
        unsigned int lo = __builtin_amdgcn_cvt_pk_fp8_f32(a.x, a.y, 0u, false);
        lo = __builtin_amdgcn_cvt_pk_fp8_f32(a.z, a.w, lo, true);
        unsigned int hi = __builtin_amdgcn_cvt_pk_fp8_f32(c.x, c.y, 0u, false);
        hi = __builtin_amdgcn_cvt_pk_fp8_f32(c.z, c.w, hi, true);
        u2v o; o.x = lo; o.y = hi;
        q[i] = o;
    }
    __shared__ float ts[8], tm[8];
    int wid = threadIdx.x >> 6, lane = threadIdx.x & 63;
    s = waveSum(s);
    m = waveMax(m);
    if (lane == 0) { ts[wid] = s; tm[wid] = m; }
    __syncthreads();
    if (threadIdx.x == 0) {
        float a = 0.f, qm = -INFINITY;
#pragma unroll
        for (int j = 0; j < 8; ++j) { a += ts[j]; qm = fmaxf(qm, tm[j]); }
        wsum2[blk] = a;
        wmax2[blk] = qm;
    }
}

// K2: CA MLP (redundant per block, combines half-plane partials) + per-pixel
// channel mean/max of ca*weight (fp8). grid=(64,16), 256 thr, 4 px/thread.
__global__ __launch_bounds__(256) void ca_spatial(const unsigned int* __restrict__ wq,
                           const float* __restrict__ wsum2, const float* __restrict__ wmax2,
                           const float* __restrict__ fc1, const float* __restrict__ fc2,
                           float* __restrict__ spm, float* __restrict__ spx,
                           float* __restrict__ ca_out) {
    int b = blockIdx.y;
    int t = threadIdx.x;
    __shared__ float hid[16];
    __shared__ float cas[64];
    if (t < 16) {
        int j = t & 7;
        float s = 0.f;
        if (t < 8) {
#pragma unroll 8
            for (int c = 0; c < 64; ++c) {
                int i2 = (b * 64 + c) * 2;
                s += fc1[j * 64 + c] * ((wsum2[i2] + wsum2[i2 + 1]) * (1.f / (float)HW_));
            }
        } else {
#pragma unroll 8
            for (int c = 0; c < 64; ++c) {
                int i2 = (b * 64 + c) * 2;
                s += fc1[j * 64 + c] * fmaxf(wmax2[i2], wmax2[i2 + 1]);
            }
        }
        hid[t] = fmaxf(s, 0.f);
    }
    __syncthreads();
    if (t < 64) {
        float o = 0.f;
#pragma unroll
        for (int j = 0; j < 8; ++j) o += (hid[j] + hid[8 + j]) * fc2[t * 8 + j];
        float c = 1.f / (1.f + expf(-o));
        cas[t] = c;
        if (blockIdx.x == 0) ca_out[b * 64 + t] = c;
    }
    __syncthreads();

    int pix4 = blockIdx.x * 256 + t;   // 4-pixel (uint) index within plane
    const unsigned int* base = wq + (size_t)b * 64 * (HW_ / 4);
    float s0 = 0.f, s1 = 0.f, s2 = 0.f, s3 = 0.f;
    float m0 = -INFINITY, m1 = -INFINITY, m2 = -INFINITY, m3 = -INFINITY;
#pragma unroll 8
    for (int c = 0; c < 64; ++c) {
        unsigned int u = base[(size_t)c * (HW_ / 4) + pix4];
        float a = cas[c];
        f2v p01 = __builtin_amdgcn_cvt_pk_f32_fp8(u, false);
        f2v p23 = __builtin_amdgcn_cvt_pk_f32_fp8(u, true);
        float v0 = a * p01.x, v1 = a * p01.y, v2 = a * p23.x, v3 = a * p23.y;
        s0 += v0; s1 += v1; s2 += v2; s3 += v3;
        m0 = fmaxf(m0, v0); m1 = fmaxf(m1, v1);
        m2 = fmaxf(m2, v2); m3 = fmaxf(m3, v3);
    }
    const float inv = 1.f / 64.f;
    ((float4*)spm)[(size_t)b * (HW_ / 4) + pix4] =
        make_float4(s0 * inv, s1 * inv, s2 * inv, s3 * inv);
    ((float4*)spx)[(size_t)b * (HW_ / 4) + pix4] = make_float4(m0, m1, m2, m3);
}

// K3: 7x7 conv over [mean,max] -> sigmoid. grid=(256,16), 256 thr (one row).
__global__ void sa_conv(const float* __restrict__ spm, const float* __restrict__ spx,
                        const float* __restrict__ sw, float* __restrict__ sa) {
    int b = blockIdx.y, y = blockIdx.x, x = threadIdx.x;
    const float* in0 = spm + (size_t)b * HW_;
    const float* in1 = spx + (size_t)b * HW_;
    float acc = 0.f;
#pragma unroll
    for (int ky = 0; ky < 7; ++ky) {
        int yy = y + ky - 3;
        if (yy < 0 || yy >= H_) continue;
        const float* r0 = in0 + yy * W_;
        const float* r1 = in1 + yy * W_;
#pragma unroll
        for (int kx = 0; kx < 7; ++kx) {
            int xx = x + kx - 3;
            if (xx < 0 || xx >= W_) continue;
            acc += r0[xx] * sw[ky * 7 + kx] + r1[xx] * sw[49 + ky * 7 + kx];
        }
    }
    sa[(size_t)b * HW_ + y * W_ + x] = 1.f / (1.f + expf(-acc));
}

// K4: half-plane partial of sum(sa * weight) from fp8. grid=2048 (XCD-chunked),
// 512 thr.
__global__ __launch_bounds__(512) void weighted_reduce(const u2v* __restrict__ wq,
                                const float* __restrict__ sa,
                                float* __restrict__ sval2) {
    int d = blockIdx.x;
    int unit = ((d & 7) << 8) + (d >> 3);   // 8 XCDs x 256 units (2 images each)
    int bc = unit >> 1, half = unit & 1;
    int b = bc >> 6;
    const u2v* wp = wq + (size_t)bc * (HW_ / 8) + half * (HW_ / 16);
    const float4* sp = (const float4*)(sa + (size_t)b * HW_ + half * (HW_ / 2));
    float s = 0.f;
#pragma unroll 4
    for (int i = threadIdx.x; i < HW_ / 16; i += 512) {
        u2v u = wp[i];
        float4 q0 = sp[2 * i], q1 = sp[2 * i + 1];
        f2v p01 = __builtin_amdgcn_cvt_pk_f32_fp8(u.x, false);
        f2v p23 = __builtin_amdgcn_cvt_pk_f32_fp8(u.x, true);
        f2v p45 = __builtin_amdgcn_cvt_pk_f32_fp8(u.y, false);
        f2v p67 = __builtin_amdgcn_cvt_pk_f32_fp8(u.y, true);
        s += p01.x * q0.x + p01.y * q0.y + p23.x * q0.z + p23.y * q0.w
           + p45.x * q1.x + p45.y * q1.y + p67.x * q1.z + p67.y * q1.w;
    }
    __shared__ float ts[8];
    int wid = threadIdx.x >> 6, lane = threadIdx.x & 63;
    s = waveSum(s);
    if (lane == 0) ts[wid] = s;
    __syncthreads();
    if (threadIdx.x == 0) {
        float a = 0.f;
#pragma unroll
        for (int j = 0; j < 8; ++j) a += ts[j];
        sval2[unit] = a;
    }
}

// K5: build per-sample kernel (combines sval2 partials) + dynamic 3x3x64 conv.
// grid=512 (16 b x 32 tiles of 8 rows, XCD-chunked), 512 thr:
// thread = (x = t&255, half-row-group = t>>8).
__global__ __launch_bounds__(512) void final_conv(const float* __restrict__ x1,
                           const float* __restrict__ ca, const float* __restrict__ sval2,
                           const float* __restrict__ pk1w, const float* __restrict__ pk1b,
                           const float* __restrict__ pk2w, const float* __restrict__ pk2b,
                           float* __restrict__ out) {
    int d = blockIdx.x;
    int gid = ((d & 7) << 6) + (d >> 3);  // 8 XCDs x 64 tiles (2 images each)
    int b = gid >> 5;
    int y0 = (gid & 31) * 8;
    int t = threadIdx.x;
    __shared__ float wg[64];
    __shared__ float kern[64][9];
    if (t < 64) {
        int i2 = (b * 64 + t) * 2;
        wg[t] = ca[b * 64 + t] * ((sval2[i2] + sval2[i2 + 1]) * (1.f / (float)HW_));
    }
    __syncthreads();
    if (t < 64) {
        float p = pk1b[t];
#pragma unroll 8
        for (int c = 0; c < 64; ++c) p += pk1w[t * 64 + c] * wg[c];
#pragma unroll
        for (int j = 0; j < 9; ++j) kern[t][j] = p * pk2w[t * 9 + j] + pk2b[t * 9 + j];
    }
    __syncthreads();

    int x = t & 255;
    int ybase = y0 + ((t >> 8) << 2);   // y0 or y0+4
    float acc[4] = {0.f, 0.f, 0.f, 0.f};

    for (int ic = 0; ic < 64; ++ic) {
        const float* plane = x1 + ((size_t)(b * 64 + ic) << 16);
        float k0 = kern[ic][0], k1 = kern[ic][1], k2 = kern[ic][2];
        float k3 = kern[ic][3], k4 = kern[ic][4], k5 = kern[ic][5];
        float k6 = kern[ic][6], k7 = kern[ic][7], k8 = kern[ic][8];
#pragma unroll
        for (int j = -1; j <= 4; ++j) {
            int yy = ybase + j;
            float m = 0.f, z = 0.f, p = 0.f;
            if (yy >= 0 && yy < H_) {
                const float* row = plane + yy * W_;
                z = row[x];
                m = (x > 0) ? row[x - 1] : 0.f;
                p = (x < W_ - 1) ? row[x + 1] : 0.f;
            }
            if (j <= 2) acc[j + 1] += m * k0 + z * k1 + p * k2;
            if (j >= 0 && j <= 3) acc[j] += m * k3 + z * k4 + p * k5;
            if (j >= 1) acc[j - 1] += m * k6 + z * k7 + p * k8;
        }
    }
#pragma unroll
    for (int r = 0; r < 4; ++r)
        out[(size_t)b * HW_ + (size_t)(ybase + r) * W_ + x] = acc[r];
}

extern "C" void kernel_launch(void* const* d_in, const int* in_sizes, int n_in,
                              void* d_out, int out_size, void* d_ws, size_t ws_size,
                              hipStream_t stream) {
    const float* x1     = (const float*)d_in[0];
    const float* weight = (const float*)d_in[1];
    const float* fc1    = (const float*)d_in[2];
    const float* fc2    = (const float*)d_in[3];
    const float* saw    = (const float*)d_in[4];
    const float* pk1w   = (const float*)d_in[5];
    const float* pk1b   = (const float*)d_in[6];
    const float* pk2w   = (const float*)d_in[7];
    const float* pk2b   = (const float*)d_in[8];
    float* out = (float*)d_out;

    float* ws    = (float*)d_ws;
    float* wsum2 = ws;                        // 2048
    float* wmax2 = ws + 2048;                 // 2048
    float* ca    = ws + 4096;                 // 1024
    float* sval2 = ws + 5120;                 // 2048
    float* spm   = ws + 16384;                // 1048576
    float* spx   = spm + (size_t)B_ * HW_;    // 1048576
    float* sa    = spx + (size_t)B_ * HW_;    // 1048576
    u2v*   wq    = (u2v*)(ws + 16384 + 3u * 1048576u);  // 67 MB fp8

    reduce_weight_q<<<dim3(2 * B_ * C_), 512, 0, stream>>>(weight, wq, wsum2, wmax2);
    ca_spatial<<<dim3(64, B_), 256, 0, stream>>>((const unsigned int*)wq, wsum2, wmax2,
                                                 fc1, fc2, spm, spx, ca);
    sa_conv<<<dim3(H_, B_), 256, 0, stream>>>(spm, spx, saw, sa);
    weighted_reduce<<<dim3(2 * B_ * C_), 512, 0, stream>>>(wq, sa, sval2);
    final_conv<<<dim3(512), 512, 0, stream>>>(x1, ca, sval2, pk1w, pk1b, pk2w, pk2b, out);
}